// Round 1
// 1154.251 us; speedup vs baseline: 1.3666x; 1.3666x over previous
//
#include <hip/hip_runtime.h>
#include <stdint.h>

#define B_  2
#define H_  4
#define T_  2048
#define N_  4096
#define BH  8          // B_*H_

// 256x256 tile, BK=64, 8 waves (2Mx4N), 8-phase counted-vmcnt schedule
#define BM 256
#define BN 256
#define BK 64

typedef __attribute__((ext_vector_type(8))) short  short8;
typedef __attribute__((ext_vector_type(4))) float  floatx4;

// ---- helpers ---------------------------------------------------------------

__device__ __forceinline__ unsigned short f2bf(float x) {
  union { float f; unsigned u; } un; un.f = x;
  unsigned r = un.u + 0x7FFFu + ((un.u >> 16) & 1u);   // round-to-nearest-even
  return (unsigned short)(r >> 16);
}

__device__ __forceinline__ void async_copy16(const void* g, void* l) {
  __builtin_amdgcn_global_load_lds(
      (const __attribute__((address_space(1))) unsigned int*)g,
      (__attribute__((address_space(3))) unsigned int*)l,
      16, 0, 0);
}

// ---- kernel 1: RoPE(Q) + cast to bf16 (unchanged) --------------------------
__global__ __launch_bounds__(256)
void rope_cast_kernel(const float* __restrict__ Q, unsigned short* __restrict__ QR) {
  const long e0 = ((long)blockIdx.x * 256 + threadIdx.x) * 8;
  const float4 v0 = *(const float4*)(Q + e0);
  const float4 v1 = *(const float4*)(Q + e0 + 4);
  const int   n0 = (int)(e0 & (N_ - 1));
  const float t  = (float)((int)((e0 >> 12) & (T_ - 1)));
  float vv[8] = {v0.x, v0.y, v0.z, v0.w, v1.x, v1.y, v1.z, v1.w};
  union { short8 v; unsigned short u[8]; } o;
#pragma unroll
  for (int p = 0; p < 4; ++p) {
    const int n = n0 + 2 * p;
    const float freq = exp2f(-(float)n * (1.0f / 256.0f)) * 0.15915494309189535f;
    const float ph = t * freq;
    const float fr = ph - floorf(ph);
    const float s = __builtin_amdgcn_sinf(fr);
    const float c = __builtin_amdgcn_cosf(fr);
    o.u[2 * p]     = f2bf(vv[2 * p] * c - vv[2 * p + 1] * s);
    o.u[2 * p + 1] = f2bf(vv[2 * p + 1] * c + vv[2 * p] * s);
  }
  *(short8*)(QR + e0) = o.v;
}

// ---- kernel 2: transpose + cast V -> Vt (unchanged) ------------------------
__global__ __launch_bounds__(256)
void transpose_cast_kernel(const float* __restrict__ V, unsigned short* __restrict__ Vt) {
  __shared__ float tile[64][65];
  const long bh = blockIdx.z;
  const float* Vb = V + bh * (long)T_ * N_;
  unsigned short* Vtb = Vt + bh * (long)N_ * T_;
  const int s0 = blockIdx.x * 64;
  const int n0 = blockIdx.y * 64;
  const int tx = threadIdx.x & 63;
  const int ty = threadIdx.x >> 6;
#pragma unroll
  for (int i = 0; i < 16; ++i) {
    const int r = ty * 16 + i;
    tile[r][tx] = Vb[(long)(s0 + r) * N_ + n0 + tx];
  }
  __syncthreads();
#pragma unroll
  for (int i = 0; i < 16; ++i) {
    const int r = ty * 16 + i;
    Vtb[(long)(n0 + r) * T_ + s0 + tx] = f2bf(tile[tx][r]);
  }
}

// ---- 256^2 8-phase GEMM (B^T layout): C = alpha * A @ B^T ------------------
// LDS tile: 256x64 bf16 per operand, stored as two 128-row halves of 16 KiB.
// Physical layout is lane-linear (global_load_lds requirement); the st-swizzle
// byte ^= ((row&7)<<4) is applied on the GLOBAL source during staging and on
// the ds_read address (both-sides involution, rule #21) -> conflict-free
// ds_read_b128 (8 lanes per 16B slot column).
__device__ __forceinline__ const short8* frag_ptr(const unsigned short* base, int row, int colel) {
  const int half = row >> 7;
  const int r    = row & 127;
  int o = r * 128 + colel * 2;          // bytes within half
  o ^= (r & 7) << 4;                    // st-swizzle
  return (const short8*)((const char*)base + half * 16384 + o);
}

__device__ __forceinline__ void load_a8(short8 a[8], const unsigned short* tp, int rb, int lr, int lk) {
#pragma unroll
  for (int f = 0; f < 4; ++f)
#pragma unroll
    for (int s = 0; s < 2; ++s)
      a[f * 2 + s] = *frag_ptr(tp, rb + f * 16 + lr, s * 32 + lk);
}

__device__ __forceinline__ void load_b4(short8 b[4], const unsigned short* tp, int rb, int lr, int lk) {
#pragma unroll
  for (int c = 0; c < 2; ++c)
#pragma unroll
    for (int s = 0; s < 2; ++s)
      b[c * 2 + s] = *frag_ptr(tp, rb + c * 16 + lr, s * 32 + lk);
}

template<int QI, int QJ>
__device__ __forceinline__ void mfma_quad(floatx4 (&acc)[8][4], const short8* a, const short8* b) {
#pragma unroll
  for (int s = 0; s < 2; ++s)
#pragma unroll
    for (int f = 0; f < 4; ++f)
#pragma unroll
      for (int c = 0; c < 2; ++c)
        acc[QI * 4 + f][QJ * 2 + c] = __builtin_amdgcn_mfma_f32_16x16x32_bf16(
            a[f * 2 + s], b[c * 2 + s], acc[QI * 4 + f][QJ * 2 + c], 0, 0, 0);
}

template <typename OutT>
__global__ __launch_bounds__(512, 2)
void gemm_bt8(const unsigned short* __restrict__ A, const unsigned short* __restrict__ B,
              OutT* __restrict__ C, int M, int Nc, int K, float alpha,
              long sA, long sB, long sC)
{
  __shared__ unsigned short smem[4][16384];   // [dbuf*2 + {A,B}] x 256x64, 128 KiB

  // T1: bijective XCD-aware block swizzle (nwg % 8 == 0 for both GEMMs)
  const int nx = (int)gridDim.x, ny = (int)gridDim.y;
  const int nwg = nx * ny * (int)gridDim.z;
  const int idx = (int)blockIdx.x + nx * ((int)blockIdx.y + ny * (int)blockIdx.z);
  const int wg = ((nwg & 7) == 0) ? ((idx & 7) * (nwg >> 3) + (idx >> 3)) : idx;
  const int bx = wg % nx;
  const int by = (wg / nx) % ny;
  const int bz = wg / (nx * ny);

  const unsigned short* Ab = A + bz * sA;
  const unsigned short* Bb = B + bz * sB;
  OutT* Cb = C + bz * sC;
  const int tM = by * BM, tN = bx * BN;

  const int tid  = (int)threadIdx.x;
  const int lane = tid & 63;
  const int wave = tid >> 6;
  const int wm = wave >> 2;                   // 0..1  (128-row slab)
  const int wn = wave & 3;                    // 0..3  (64-col slab)
  const int lr = lane & 15;
  const int lk = (lane >> 4) * 8;

  // staging geometry: physical LDS is lane-linear; global source carries the
  // inverse swizzle.  p = j*8192 + wave*1024 + lane*16  ->
  // row = j*64 + wave*8 + (lane>>3), colel = (((lane&7)*16) ^ ((lane>>3)<<4))>>1
  const int sr = wave * 8 + (lane >> 3);
  const int sc = ((((lane & 7) * 16) ^ ((lane >> 3) << 4)) >> 1);
  const long aoff = (long)(tM + sr) * K + sc;
  const long boff = (long)(tN + sr) * K + sc;
  const int NT = K / BK;

  #define STAGE(Gb, off, kt, h, Lhalf) do {                                        \
    const unsigned short* _g = (Gb) + (off) + (long)(h) * 128 * K + (long)(kt) * 64; \
    async_copy16(_g,                &(Lhalf)[wave * 512]);                          \
    async_copy16(_g + (long)64 * K, &(Lhalf)[4096 + wave * 512]);                   \
  } while (0)

  // prologue: B(0) h0,h1 | A(0) h0,h1 | B(1) h0,h1 ; wait all but newest 2 halves
  STAGE(Bb, boff, 0, 0, &smem[1][0]);
  STAGE(Bb, boff, 0, 1, &smem[1][8192]);
  STAGE(Ab, aoff, 0, 0, &smem[0][0]);
  STAGE(Ab, aoff, 0, 1, &smem[0][8192]);
  const int k1 = (NT > 1) ? 1 : 0;
  STAGE(Bb, boff, k1, 0, &smem[3][0]);
  STAGE(Bb, boff, k1, 1, &smem[3][8192]);
  asm volatile("s_waitcnt vmcnt(4)" ::: "memory");
  __builtin_amdgcn_s_barrier();

  floatx4 acc[8][4] = {};
  short8 a[8], b0[4], b1[4];

  // Stage stream: A-halves of tile t+1 at phases 0/1 (-> buf^1),
  //               B-halves of tile t+2 at phases 2/3 (-> buf cur; those regions
  //               are dead: all B reads of cur complete by end of phase 1 since
  //               the qj=0 B-frags are held in registers through phase 3).
  for (int t = 0; t < NT; ++t) {
    const unsigned short* Ac = smem[(t & 1) * 2 + 0];
    const unsigned short* Bc = smem[(t & 1) * 2 + 1];
    unsigned short* An = smem[((t + 1) & 1) * 2 + 0];
    unsigned short* Bn = smem[(t & 1) * 2 + 1];          // tile t+2, same parity
    const int ktA = (t + 1 < NT) ? t + 1 : NT - 1;       // clamped: tail loads are
    const int ktB = (t + 2 < NT) ? t + 2 : NT - 1;       // never read, keep counts uniform

    // phase 0: quad (0,0)
    load_a8(a,  Ac, wm * 128 + 0,  lr, lk);
    load_b4(b0, Bc, wn * 64 + 0,   lr, lk);
    STAGE(Ab, aoff, ktA, 0, &An[0]);
    __builtin_amdgcn_s_barrier();
    asm volatile("s_waitcnt lgkmcnt(0)" ::: "memory");
    __builtin_amdgcn_s_setprio(1);
    mfma_quad<0, 0>(acc, a, b0);
    __builtin_amdgcn_s_setprio(0);
    __builtin_amdgcn_s_barrier();

    // phase 1: quad (0,1)
    load_b4(b1, Bc, wn * 64 + 32, lr, lk);
    STAGE(Ab, aoff, ktA, 1, &An[8192]);
    __builtin_amdgcn_s_barrier();
    asm volatile("s_waitcnt lgkmcnt(0)" ::: "memory");
    __builtin_amdgcn_s_setprio(1);
    mfma_quad<0, 1>(acc, a, b1);
    __builtin_amdgcn_s_setprio(0);
    __builtin_amdgcn_s_barrier();

    // phase 2: quad (1,1)
    load_a8(a, Ac, wm * 128 + 64, lr, lk);
    STAGE(Bb, boff, ktB, 0, &Bn[0]);
    __builtin_amdgcn_s_barrier();
    asm volatile("s_waitcnt lgkmcnt(0)" ::: "memory");
    __builtin_amdgcn_s_setprio(1);
    mfma_quad<1, 1>(acc, a, b1);
    __builtin_amdgcn_s_setprio(0);
    __builtin_amdgcn_s_barrier();

    // phase 3: quad (1,0) — b0 held in regs since phase 0; counted boundary wait
    STAGE(Bb, boff, ktB, 1, &Bn[8192]);
    asm volatile("s_waitcnt vmcnt(4)" ::: "memory");
    __builtin_amdgcn_s_barrier();
    __builtin_amdgcn_s_setprio(1);
    mfma_quad<1, 0>(acc, a, b0);
    __builtin_amdgcn_s_setprio(0);
    __builtin_amdgcn_s_barrier();
  }
  #undef STAGE

  // epilogue: D mapping col = lane&15, row = (lane>>4)*4 + r
  const int crow = (lane >> 4) * 4;
  const int ccol = lane & 15;
#pragma unroll
  for (int f = 0; f < 8; ++f)
#pragma unroll
    for (int c = 0; c < 4; ++c)
#pragma unroll
      for (int r = 0; r < 4; ++r) {
        const long row = tM + wm * 128 + f * 16 + crow + r;
        const long col = tN + wn * 64 + c * 16 + ccol;
        const float v = acc[f][c][r] * alpha;
        OutT* p = &Cb[row * (long)Nc + col];
        if constexpr (sizeof(OutT) == 2) *p = (OutT)f2bf(v);
        else                             *p = (OutT)v;
      }
}

// ---- launch ----------------------------------------------------------------
extern "C" void kernel_launch(void* const* d_in, const int* in_sizes, int n_in,
                              void* d_out, int out_size, void* d_ws, size_t ws_size,
                              hipStream_t stream) {
  const float* Q = (const float*)d_in[0];
  // d_in[1] (K) is unused by the reference.
  const float* V = (const float*)d_in[2];
  float* O = (float*)d_out;

  // workspace layout: QRb (134MB) | Vtb (134MB) | S (64MB)  => ~320 MiB
  unsigned short* QRb = (unsigned short*)d_ws;
  unsigned short* Vtb = QRb + (size_t)BH * T_ * N_;
  unsigned short* S   = Vtb + (size_t)BH * T_ * N_;

  // 1. RoPE(Q) -> bf16
  rope_cast_kernel<<<(BH * (long)T_ * N_) / (8 * 256), 256, 0, stream>>>(Q, QRb);
  // 2. V -> Vt (bf16)
  transpose_cast_kernel<<<dim3(T_ / 64, N_ / 64, BH), 256, 0, stream>>>(V, Vtb);
  // 3. S = (1/64) * QR @ QR^T   [per bh: 2048x2048, K=4096]
  gemm_bt8<unsigned short><<<dim3(T_ / BN, T_ / BM, BH), 512, 0, stream>>>(
      QRb, QRb, S, T_, T_, N_, 1.0f / 64.0f,
      (long)T_ * N_, (long)T_ * N_, (long)T_ * T_);
  // 4. O = S @ Vt^T             [per bh: 2048x4096, K=2048]
  gemm_bt8<float><<<dim3(N_ / BN, T_ / BM, BH), 512, 0, stream>>>(
      S, Vtb, O, T_, N_, T_, 1.0f,
      (long)T_ * T_, (long)N_ * T_, (long)T_ * N_);
}

// Round 3
// 1151.281 us; speedup vs baseline: 1.3701x; 1.0026x over previous
//
#include <hip/hip_runtime.h>
#include <stdint.h>

#define B_  2
#define H_  4
#define T_  2048
#define N_  4096
#define BH  8          // B_*H_

// 256x256 tile, BK=64, 8 waves (2Mx4N), 4-phase counted-vmcnt schedule
#define BM 256
#define BN 256
#define BK 64

#define ROPE_BLOCKS  ((BH * (long)T_ * N_) / (8 * 256))   // 32768
#define TRANS_BLOCKS ((T_ / 64) * (N_ / 64) * BH)         // 16384

typedef __attribute__((ext_vector_type(8))) short  short8;
typedef __attribute__((ext_vector_type(4))) float  floatx4;

// ---- helpers ---------------------------------------------------------------

__device__ __forceinline__ unsigned short f2bf(float x) {
  union { float f; unsigned u; } un; un.f = x;
  unsigned r = un.u + 0x7FFFu + ((un.u >> 16) & 1u);   // round-to-nearest-even
  return (unsigned short)(r >> 16);
}

__device__ __forceinline__ void async_copy16(const void* g, void* l) {
  __builtin_amdgcn_global_load_lds(
      (const __attribute__((address_space(1))) unsigned int*)g,
      (__attribute__((address_space(3))) unsigned int*)l,
      16, 0, 0);
}

// ---- fused prep: RoPE(Q)->bf16  and  V -> Vt (bf16), block-partitioned -----
// blocks [0, ROPE_BLOCKS): rope;  [ROPE_BLOCKS, +TRANS_BLOCKS): transpose.
__global__ __launch_bounds__(256)
void prep_kernel(const float* __restrict__ Q, unsigned short* __restrict__ QR,
                 const float* __restrict__ V, unsigned short* __restrict__ Vt) {
  __shared__ float tile[64][65];
  const int bid = (int)blockIdx.x;

  if (bid < (int)ROPE_BLOCKS) {
    // ---- RoPE(Q) + cast ----
    const long e0 = ((long)bid * 256 + threadIdx.x) * 8;
    const float4 v0 = *(const float4*)(Q + e0);
    const float4 v1 = *(const float4*)(Q + e0 + 4);
    const int   n0 = (int)(e0 & (N_ - 1));
    const float t  = (float)((int)((e0 >> 12) & (T_ - 1)));
    float vv[8] = {v0.x, v0.y, v0.z, v0.w, v1.x, v1.y, v1.z, v1.w};
    union { short8 v; unsigned short u[8]; } o;
#pragma unroll
    for (int p = 0; p < 4; ++p) {
      const int n = n0 + 2 * p;
      const float freq = exp2f(-(float)n * (1.0f / 256.0f)) * 0.15915494309189535f;
      const float ph = t * freq;
      const float fr = ph - floorf(ph);
      const float s = __builtin_amdgcn_sinf(fr);
      const float c = __builtin_amdgcn_cosf(fr);
      o.u[2 * p]     = f2bf(vv[2 * p] * c - vv[2 * p + 1] * s);
      o.u[2 * p + 1] = f2bf(vv[2 * p + 1] * c + vv[2 * p] * s);
    }
    *(short8*)(QR + e0) = o.v;
  } else {
    // ---- V transpose + cast, vectorized both sides ----
    const int tb = bid - (int)ROPE_BLOCKS;
    const int sxi = tb & 31;                 // T_/64 = 32
    const int nyi = (tb >> 5) & 63;          // N_/64 = 64
    const long bh = tb >> 11;
    const float* Vb = V + bh * (long)T_ * N_;
    unsigned short* Vtb = Vt + bh * (long)N_ * T_;
    const int s0 = sxi * 64;
    const int n0 = nyi * 64;
    const int c = threadIdx.x & 15;          // n-quad 0..15
    const int r = threadIdx.x >> 4;          // s-row 0..15
#pragma unroll
    for (int i = 0; i < 4; ++i) {
      const float4 v = *(const float4*)(Vb + (long)(s0 + r + 16 * i) * N_ + n0 + c * 4);
      tile[r + 16 * i][c * 4 + 0] = v.x;
      tile[r + 16 * i][c * 4 + 1] = v.y;
      tile[r + 16 * i][c * 4 + 2] = v.z;
      tile[r + 16 * i][c * 4 + 3] = v.w;
    }
    __syncthreads();
    const int rn = threadIdx.x >> 3;         // n 0..31
    const int cs = threadIdx.x & 7;          // s-octet 0..7
#pragma unroll
    for (int i = 0; i < 2; ++i) {
      const int n = rn + 32 * i;
      union { short8 v; unsigned short u[8]; } o;
#pragma unroll
      for (int k = 0; k < 8; ++k) o.u[k] = f2bf(tile[cs * 8 + k][n]);
      *(short8*)(Vtb + (long)(n0 + n) * T_ + s0 + cs * 8) = o.v;
    }
  }
}

// ---- 256^2 4-phase GEMM (B^T layout): C = alpha * A @ B^T ------------------
// LDS: per operand 256x64 bf16 as two 128-row halves of 16 KiB; lane-linear
// physical layout (global_load_lds), st-swizzle byte^=((row&7)<<4) carried by
// the pre-swizzled GLOBAL source + swizzled ds_read address (rule #21).
// Byte map: A-par0 @0 (h1 +16384), B-par0 @32768, parity toggle ^0x10000.
// Phase schedule is the r1-verified one: reads; STAGE; s_barrier; lgkmcnt(0);
// setprio MFMA; s_barrier.  (r2's thinned-barrier variant raced: compiler may
// sink ds_reads/MFMA past a raw s_barrier -> WAR vs next phase's staging.)
template<int QI, int QJ>
__device__ __forceinline__ void mfma_quad(floatx4 (&acc)[8][4], const short8* a, const short8* b) {
#pragma unroll
  for (int s = 0; s < 2; ++s)
#pragma unroll
    for (int f = 0; f < 4; ++f)
#pragma unroll
      for (int c = 0; c < 2; ++c)
        acc[QI * 4 + f][QJ * 2 + c] = __builtin_amdgcn_mfma_f32_16x16x32_bf16(
            a[f * 2 + s], b[c * 2 + s], acc[QI * 4 + f][QJ * 2 + c], 0, 0, 0);
}

template <typename OutT>
__global__ __launch_bounds__(512, 2)
void gemm_bt8(const unsigned short* __restrict__ A, const unsigned short* __restrict__ B,
              OutT* __restrict__ C, int M, int Nc, int K, float alpha,
              long sA, long sB, long sC)
{
  __shared__ unsigned short smem[4][16384];   // 128 KiB
  char* smemb = (char*)smem;

  // T1: bijective XCD-aware block swizzle (nwg % 8 == 0 for both GEMMs)
  const int nx = (int)gridDim.x, ny = (int)gridDim.y;
  const int nwg = nx * ny * (int)gridDim.z;
  const int idx = (int)blockIdx.x + nx * ((int)blockIdx.y + ny * (int)blockIdx.z);
  const int wg = ((nwg & 7) == 0) ? ((idx & 7) * (nwg >> 3) + (idx >> 3)) : idx;
  const int bx = wg % nx;
  const int by = (wg / nx) % ny;
  const int bz = wg / (nx * ny);

  const unsigned short* Ab = A + bz * sA;
  const unsigned short* Bb = B + bz * sB;
  OutT* Cb = C + bz * sC;
  const int tM = by * BM, tN = bx * BN;

  const int tid  = (int)threadIdx.x;
  const int lane = tid & 63;
  const int wave = tid >> 6;
  const int wm = wave >> 2;                   // 0..1  (128-row slab)
  const int wn = wave & 3;                    // 0..3  (64-col slab)
  const int lr = lane & 15;
  const int lk = (lane >> 4) * 8;

  // strength-reduced ds_read bases: swizzle XOR term (r&7)<<4 == (lane&7)<<4 is
  // row-invariant per lane, so 4 base pointers + constant offsets cover all 24
  // fragment reads (validated: r2 initial correctness passed, absmax 4.0).
  const unsigned swz   = (unsigned)(lane & 7) << 4;
  const unsigned lowA0 = ((unsigned)(lk * 2)     ) ^ swz;
  const unsigned lowA1 = ((unsigned)(lk * 2) + 64) ^ swz;
  const unsigned aB4   = (unsigned)wm * 16384u + (unsigned)lr * 128u;
  const unsigned bB4   = 32768u + (unsigned)(wn >> 1) * 16384u
                       + (unsigned)(wn & 1) * 8192u + (unsigned)lr * 128u;

  // staging geometry: linear LDS dest + inverse-swizzled source (rule #21)
  const int sr = wave * 8 + (lane >> 3);
  const int sc = ((((lane & 7) * 16) ^ ((lane >> 3) << 4)) >> 1);
  const unsigned short* gA = Ab + (long)(tM + sr) * K + sc;
  const unsigned short* gB = Bb + (long)(tN + sr) * K + sc;
  const int NT = K / BK;

  #define STAGE2(gbase, kt, h, ldst) do {                                          \
    const unsigned short* _g = (gbase) + (long)(kt) * 64 + (long)((h) * 128) * K;  \
    async_copy16(_g,                (char*)(ldst) + wave * 1024);                  \
    async_copy16(_g + (long)64 * K, (char*)(ldst) + 8192 + wave * 1024);           \
  } while (0)

  // prologue: B(0) h0,h1 | A(0) h0,h1 | B(1) h0,h1 ; wait all but newest 2 halves
  STAGE2(gB, 0, 0, smemb + 32768);
  STAGE2(gB, 0, 1, smemb + 32768 + 16384);
  STAGE2(gA, 0, 0, smemb + 0);
  STAGE2(gA, 0, 1, smemb + 16384);
  const int k1 = (NT > 1) ? 1 : 0;
  STAGE2(gB, k1, 0, smemb + 65536 + 32768);
  STAGE2(gB, k1, 1, smemb + 65536 + 32768 + 16384);
  asm volatile("s_waitcnt vmcnt(4)" ::: "memory");
  __builtin_amdgcn_s_barrier();

  floatx4 acc[8][4] = {};
  short8 a[8], b0[4], b1[4];

  // Stage stream: A-halves of tile t+1 at phases 0/1 (-> buf^1),
  //               B-halves of tile t+2 at phases 2/3 (-> buf cur; regions dead:
  //               all B reads of cur drain by each wave's lgkmcnt(0) before the
  //               phase-1-closing barrier; b0 is register-held through phase 3).
  for (int t = 0; t < NT; ++t) {
    const unsigned par  = (unsigned)(t & 1) << 16;
    const unsigned parn = par ^ 0x10000u;
    const char* pa0 = smemb + (par + aB4 + lowA0);
    const char* pa1 = smemb + (par + aB4 + lowA1);
    const char* pb0 = smemb + (par + bB4 + lowA0);
    const char* pb1 = smemb + (par + bB4 + lowA1);
    const int ktA = (t + 1 < NT) ? t + 1 : NT - 1;   // tail loads clamped:
    const int ktB = (t + 2 < NT) ? t + 2 : NT - 1;   // never read, counts uniform

    // phase 0: quad (0,0) — A rows 0-63, B cols 0-31
#pragma unroll
    for (int f = 0; f < 4; ++f) {
      a[f * 2 + 0] = *(const short8*)(pa0 + f * 2048);
      a[f * 2 + 1] = *(const short8*)(pa1 + f * 2048);
    }
#pragma unroll
    for (int c = 0; c < 2; ++c) {
      b0[c * 2 + 0] = *(const short8*)(pb0 + c * 2048);
      b0[c * 2 + 1] = *(const short8*)(pb1 + c * 2048);
    }
    STAGE2(gA, ktA, 0, smemb + parn);
    __builtin_amdgcn_s_barrier();
    asm volatile("s_waitcnt lgkmcnt(0)" ::: "memory");
    __builtin_amdgcn_s_setprio(1);
    mfma_quad<0, 0>(acc, a, b0);
    __builtin_amdgcn_s_setprio(0);
    __builtin_amdgcn_s_barrier();

    // phase 1: quad (0,1) — B cols 32-63
#pragma unroll
    for (int c = 0; c < 2; ++c) {
      b1[c * 2 + 0] = *(const short8*)(pb0 + 4096 + c * 2048);
      b1[c * 2 + 1] = *(const short8*)(pb1 + 4096 + c * 2048);
    }
    STAGE2(gA, ktA, 1, smemb + parn + 16384);
    __builtin_amdgcn_s_barrier();
    asm volatile("s_waitcnt lgkmcnt(0)" ::: "memory");
    __builtin_amdgcn_s_setprio(1);
    mfma_quad<0, 1>(acc, a, b1);
    __builtin_amdgcn_s_setprio(0);
    __builtin_amdgcn_s_barrier();

    // phase 2: quad (1,1) — A rows 64-127
#pragma unroll
    for (int f = 0; f < 4; ++f) {
      a[f * 2 + 0] = *(const short8*)(pa0 + 8192 + f * 2048);
      a[f * 2 + 1] = *(const short8*)(pa1 + 8192 + f * 2048);
    }
    STAGE2(gB, ktB, 0, smemb + par + 32768);
    __builtin_amdgcn_s_barrier();
    asm volatile("s_waitcnt lgkmcnt(0)" ::: "memory");
    __builtin_amdgcn_s_setprio(1);
    mfma_quad<1, 1>(acc, a, b1);
    __builtin_amdgcn_s_setprio(0);
    __builtin_amdgcn_s_barrier();

    // phase 3: quad (1,0) — b0 held in regs since phase 0; counted boundary wait
    STAGE2(gB, ktB, 1, smemb + par + 32768 + 16384);
    asm volatile("s_waitcnt vmcnt(4)" ::: "memory");
    __builtin_amdgcn_s_barrier();
    __builtin_amdgcn_s_setprio(1);
    mfma_quad<1, 0>(acc, a, b0);
    __builtin_amdgcn_s_setprio(0);
    __builtin_amdgcn_s_barrier();
  }
  #undef STAGE2

  // epilogue: D mapping col = lane&15, row = (lane>>4)*4 + r
  const int crow = (lane >> 4) * 4;
  const int ccol = lane & 15;
#pragma unroll
  for (int f = 0; f < 8; ++f)
#pragma unroll
    for (int c = 0; c < 4; ++c)
#pragma unroll
      for (int r = 0; r < 4; ++r) {
        const long row = tM + wm * 128 + f * 16 + crow + r;
        const long col = tN + wn * 64 + c * 16 + ccol;
        const float v = acc[f][c][r] * alpha;
        OutT* p = &Cb[row * (long)Nc + col];
        if constexpr (sizeof(OutT) == 2) *p = (OutT)f2bf(v);
        else                             *p = (OutT)v;
      }
}

// ---- launch ----------------------------------------------------------------
extern "C" void kernel_launch(void* const* d_in, const int* in_sizes, int n_in,
                              void* d_out, int out_size, void* d_ws, size_t ws_size,
                              hipStream_t stream) {
  const float* Q = (const float*)d_in[0];
  // d_in[1] (K) is unused by the reference.
  const float* V = (const float*)d_in[2];
  float* O = (float*)d_out;

  // workspace layout: QRb (134MB) | Vtb (134MB) | S (64MB)  => ~320 MiB
  unsigned short* QRb = (unsigned short*)d_ws;
  unsigned short* Vtb = QRb + (size_t)BH * T_ * N_;
  unsigned short* S   = Vtb + (size_t)BH * T_ * N_;

  // 1+2. fused: RoPE(Q) -> bf16  and  V -> Vt (bf16)
  prep_kernel<<<(int)(ROPE_BLOCKS + TRANS_BLOCKS), 256, 0, stream>>>(Q, QRb, V, Vtb);
  // 3. S = (1/64) * QR @ QR^T   [per bh: 2048x2048, K=4096]
  gemm_bt8<unsigned short><<<dim3(T_ / BN, T_ / BM, BH), 512, 0, stream>>>(
      QRb, QRb, S, T_, T_, N_, 1.0f / 64.0f,
      (long)T_ * N_, (long)T_ * N_, (long)T_ * T_);
  // 4. O = S @ Vt^T             [per bh: 2048x4096, K=2048]
  gemm_bt8<float><<<dim3(N_ / BN, T_ / BM, BH), 512, 0, stream>>>(
      S, Vtb, O, T_, N_, T_, 1.0f,
      (long)T_ * T_, (long)N_ * T_, (long)T_ * N_);
}